// Round 8
// baseline (1311.373 us; speedup 1.0000x reference)
//
#include <hip/hip_runtime.h>
#include <cmath>
#include <cstdint>

typedef __bf16 bf16_t;
typedef __bf16 bf16x8 __attribute__((ext_vector_type(8)));
typedef __bf16 bf16x4 __attribute__((ext_vector_type(4)));
typedef float  f32x4  __attribute__((ext_vector_type(4)));

#define DEPTH 6
#define DIM   768
#define HEADS 12
#define DH    64
#define MLPD  3072
#define SEQ   1024
#define BATCH 4
#define MTOT  (BATCH*SEQ)   /* 4096 rows */
#define QKVN  2304          /* 3*768 */

static __device__ __forceinline__ bf16x8 ld8(const bf16_t* p) {
    return *(const bf16x8*)p;
}

// async global->LDS, 16B per lane. LDS dest is wave-uniform base + lane*16.
// We permute *source* addresses per lane to build XOR-swizzled LDS layouts.
typedef const __attribute__((address_space(1))) unsigned int gas_u32;
typedef __attribute__((address_space(3))) unsigned int las_u32;
static __device__ __forceinline__ void gload16(const bf16_t* g, bf16_t* l) {
    __builtin_amdgcn_global_load_lds((gas_u32*)g, (las_u32*)l, 16, 0, 0);
}

// ---------------- fp32 [K][N] -> bf16 [N][K] transposed weight ----------------
__global__ __launch_bounds__(256) void tcvt_kernel(const float* __restrict__ in,
                                                   bf16_t* __restrict__ out,
                                                   int K, int N) {
    __shared__ float ts[32][33];
    int n0 = blockIdx.x * 32, k0 = blockIdx.y * 32;
    size_t base = (size_t)blockIdx.z * K * N;
    int tx = threadIdx.x & 31, ty = threadIdx.x >> 5;   // 32 x 8
    #pragma unroll
    for (int r = 0; r < 32; r += 8)
        ts[ty + r][tx] = in[base + (size_t)(k0 + ty + r) * N + n0 + tx];
    __syncthreads();
    #pragma unroll
    for (int r = 0; r < 32; r += 8)
        out[base + (size_t)(n0 + ty + r) * K + k0 + tx] = (bf16_t)ts[tx][ty + r];
}

// ------- fused: x += bias + sum(partials); write x and LN(x), float4 lanes ---
// 192 threads, one float4 column-group each. nslices==0: pure LN.
__global__ __launch_bounds__(192) void lnr_kernel(const float* __restrict__ xin,
                                                  float* __restrict__ xout,
                                                  const float* __restrict__ P,
                                                  int nslices,
                                                  const float* __restrict__ bias,
                                                  const float* __restrict__ w,
                                                  const float* __restrict__ b,
                                                  bf16_t* __restrict__ h,
                                                  int writeLN) {
    int row = blockIdx.x, t = threadIdx.x;
    size_t r4 = (size_t)row * 192 + t;
    float4 v = ((const float4*)xin)[r4];
    if (nslices) {
        float4 bi = ((const float4*)bias)[t];
        v.x += bi.x; v.y += bi.y; v.z += bi.z; v.w += bi.w;
        for (int s = 0; s < nslices; s++) {
            float4 pv = ((const float4*)P)[(size_t)s * MTOT * 192 + r4];
            v.x += pv.x; v.y += pv.y; v.z += pv.z; v.w += pv.w;
        }
        ((float4*)xout)[r4] = v;
    }
    float s = v.x + v.y + v.z + v.w;
    float q = v.x * v.x + v.y * v.y + v.z * v.z + v.w * v.w;
    #pragma unroll
    for (int off = 32; off > 0; off >>= 1) {
        s += __shfl_down(s, off);
        q += __shfl_down(q, off);
    }
    __shared__ float ss[3], sq[3], stat[2];
    if ((t & 63) == 0) { ss[t >> 6] = s; sq[t >> 6] = q; }
    __syncthreads();
    if (t == 0) {
        float S = ss[0] + ss[1] + ss[2];
        float Q = sq[0] + sq[1] + sq[2];
        float mean = S * (1.0f / DIM);
        float var  = Q * (1.0f / DIM) - mean * mean;
        stat[0] = mean;
        stat[1] = rsqrtf(var + 1e-5f);
    }
    __syncthreads();
    if (writeLN) {
        float mean = stat[0], rstd = stat[1];
        float4 wv4 = ((const float4*)w)[t];
        float4 bv4 = ((const float4*)b)[t];
        bf16x4 o;
        o[0] = (bf16_t)((v.x - mean) * rstd * wv4.x + bv4.x);
        o[1] = (bf16_t)((v.y - mean) * rstd * wv4.y + bv4.y);
        o[2] = (bf16_t)((v.z - mean) * rstd * wv4.z + bv4.z);
        o[3] = (bf16_t)((v.w - mean) * rstd * wv4.w + bv4.w);
        *(bf16x4*)&h[(size_t)row * DIM + t * 4] = o;
    }
}

// ---------------- bf16 MFMA GEMM: 8-wave 256x64 tile, single-round grids -----
// A: [M][K] bf16, Bt: [N][K] bf16. BM=256, BN=64, BK=32, 2-buf LDS (40KB).
// STRUCTURAL change (r8): 512 threads / 8 waves (4m x 2n, each wave 64x32 out).
//   - 40KB LDS -> exactly 4 blocks/CU -> 32 waves/CU (100% occupancy).
//   - All grids fit ONE resident round (<=1024 blocks): no sequential rounds,
//     no tail; 4 independent blocks/CU interleave across barrier stalls.
//   - 64 MFMAs per block per barrier (2.1x the old 128-row block).
// Per iter: __syncthreads (waits own tile's DMA) -> stage(it+1) async ->
// ds_read + 8 MFMA/wave.
// LDS layout: row-major [rows][32], chunk pos = chunk ^ ((row>>1)&3).
// XCD swizzle retained from r7 (null but in best-total build, zero cost).
// EPI 0: Cb = A@B; V-tiles (n0>=1536) store transposed into Vt  (QKV)
// EPI 1: Cb = gelu(A@B+bias)                                    (MLP1)
// EPI 2: Cf[slice] = A@B  (plain fp32 partial store, split-K)   (proj/MLP2)
template <int EPI>
__global__ __launch_bounds__(512) void gemm_kernel(const bf16_t* __restrict__ A,
                                                   const bf16_t* __restrict__ Bt,
                                                   const float* __restrict__ bias,
                                                   bf16_t* __restrict__ Cb,
                                                   float* __restrict__ Cf,
                                                   bf16_t* __restrict__ Vt,
                                                   int N, int K, int klen) {
    __shared__ __align__(16) bf16_t As[2][256 * 32];
    __shared__ __align__(16) bf16_t Bs[2][64 * 32];
    int t = threadIdx.x;
    // XCD-locality remap (bijective: gridDim.y=16, 16%8==0)
    int NX = gridDim.x;
    int flat = blockIdx.y * NX + blockIdx.x;
    int jj = flat >> 3;
    int bxs = jj % NX;
    int bys = (flat & 7) + ((jj / NX) << 3);
    int m0 = bys * 256, n0 = bxs * 64;
    int kz = blockIdx.z;
    int kbeg = kz * klen;
    int lane = t & 63, l16 = lane & 15, quad = lane >> 4;
    int wv = t >> 6;                    // 0..7
    int wm = wv >> 1, wn = wv & 1;      // 4 x 2 wave grid; wave = 64x32 out
    f32x4 acc[4][2] = {};

    // staging: wave wv stages A rows wv*32..wv*32+31 (two 1KB instrs);
    // waves 0..3 stage B rows wv*16..wv*16+15 (one instr).
    // lane ln -> row ln>>2 in 16-row group, LDS chunk-pos ln&3 holds global
    // chunk (ln&3)^((ln>>3)&3)  [= pos ^ ((row>>1)&3)].
    int sr = lane >> 2;
    int sc = ((lane & 3) ^ ((lane >> 3) & 3)) * 8;
    const bf16_t* gA0 = A  + (size_t)(m0 + wv * 32 + sr) * K + sc;
    const bf16_t* gA1 = gA0 + (size_t)16 * K;
    const bf16_t* gB0 = Bt + (size_t)(n0 + (wv & 3) * 16 + sr) * K + sc;
    bf16_t* lA0 = &As[0][(wv * 32) * 32];
    bf16_t* lA1 = &As[0][(wv * 32 + 16) * 32];
    bf16_t* lB0 = &Bs[0][((wv & 3) * 16) * 32];
    constexpr int bufA = 256 * 32;
    constexpr int bufB = 64 * 32;

    auto stage = [&](int buf, int k0) {
        gload16(gA0 + k0, lA0 + buf * bufA);
        gload16(gA1 + k0, lA1 + buf * bufA);
        if (wv < 4) gload16(gB0 + k0, lB0 + buf * bufB);
    };

    int nIt = klen >> 5;
    stage(0, kbeg);
    int posA = (quad ^ ((l16 >> 1) & 3)) * 8;   // swizzled frag chunk (2-way)

    for (int it = 0; it < nIt; it++) {
        __syncthreads();   // drains own DMA -> buf[it&1] ready; other buf free
        if (it + 1 < nIt) stage((it + 1) & 1, kbeg + (it + 1) * 32);
        const bf16_t* as = As[it & 1];
        const bf16_t* bs = Bs[it & 1];
        bf16x8 af[4], bfr[2];
        #pragma unroll
        for (int i = 0; i < 4; i++)
            af[i] = ld8(&as[(wm * 64 + i * 16 + l16) * 32 + posA]);
        #pragma unroll
        for (int j = 0; j < 2; j++)
            bfr[j] = ld8(&bs[(wn * 32 + j * 16 + l16) * 32 + posA]);
        #pragma unroll
        for (int i = 0; i < 4; i++)
            #pragma unroll
            for (int j = 0; j < 2; j++)
                acc[i][j] = __builtin_amdgcn_mfma_f32_16x16x32_bf16(af[i], bfr[j], acc[i][j], 0, 0, 0);
    }

    if constexpr (EPI == 0) {
        if (n0 >= 1536) {
            // V tile: store transposed into Vt[b][h][d][n], 8B per store.
            // m0 multiple of 256 -> tile never crosses a batch boundary.
            int b = m0 >> 10;
            #pragma unroll
            for (int i = 0; i < 4; i++) {
                int n = (m0 & 1023) + wm * 64 + i * 16 + quad * 4;
                #pragma unroll
                for (int j = 0; j < 2; j++) {
                    int hc = n0 + wn * 32 + j * 16 + l16 - 1536;
                    int hh = hc >> 6, d = hc & 63;
                    bf16x4 ov;
                    #pragma unroll
                    for (int r = 0; r < 4; r++) ov[r] = (bf16_t)acc[i][j][r];
                    *(bf16x4*)&Vt[(((size_t)b * HEADS + hh) * 64 + d) * SEQ + n] = ov;
                }
            }
            return;
        }
    }
    #pragma unroll
    for (int i = 0; i < 4; i++) {
        int grow = m0 + wm * 64 + i * 16 + quad * 4;
        #pragma unroll
        for (int j = 0; j < 2; j++) {
            int gcol = n0 + wn * 32 + j * 16 + l16;
            float bv = 0.0f;
            if constexpr (EPI == 1) bv = bias[gcol];
            #pragma unroll
            for (int r = 0; r < 4; r++) {
                size_t idx = (size_t)(grow + r) * N + gcol;
                float v = acc[i][j][r];
                if constexpr (EPI == 0) {
                    Cb[idx] = (bf16_t)v;
                } else if constexpr (EPI == 1) {
                    v += bv;
                    v = 0.5f * v * (1.0f + erff(v * 0.70710678118654752f));
                    Cb[idx] = (bf16_t)v;
                } else {
                    Cf[(size_t)kz * MTOT * N + idx] = v;   // plain partial store
                }
            }
        }
    }
}

// ---------------- flash attention v4: swizzled dbuf K/V + prefetch ----------
// Block = (b, h, 64 queries); wave wv owns 16 queries over full key range.
// K/V tiles [64][64] XOR-swizzled (pos = chunk^(row&7), 2-way banks),
// double-buffered; per iter: barrier -> prefetch next -> compute.
// XCD-locality swizzle kept from r7 (best-total build).
__global__ __launch_bounds__(256) void attn_kernel(const bf16_t* __restrict__ qkv,
                                                   const bf16_t* __restrict__ vt,
                                                   bf16_t* __restrict__ out) {
    int flat = (blockIdx.z * gridDim.y + blockIdx.y) * gridDim.x + blockIdx.x;
    int jj = flat >> 3;
    int qt = jj & 15;                       // gridDim.x == 16
    int bh = (flat & 7) + ((jj >> 4) << 3); // in [0, 48)
    int h = bh % HEADS, b = bh / HEADS;
    int t = threadIdx.x;
    int wv = t >> 6, lane = t & 63, l16 = lane & 15, quad = lane >> 4;
    const float LOG2E = 1.44269504f;
    int qw0 = qt * 64 + wv * 16;

    __shared__ __align__(16) bf16_t Ks[2][64 * 64];
    __shared__ __align__(16) bf16_t Vs[2][64 * 64];
    __shared__ __align__(16) bf16_t Pa[4][16 * 72];
    bf16_t* P = Pa[wv];

    size_t bS = (size_t)b * SEQ;
    const bf16_t* qrow = qkv + (bS + qw0 + l16) * QKVN + h * 64;
    bf16x8 qf0 = ld8(qrow + quad * 8);
    bf16x8 qf1 = ld8(qrow + 32 + quad * 8);

    float m = -3e38f, l = 0.0f;
    f32x4 o[4] = {};

    const bf16_t* kbase = qkv + bS * QKVN + 768 + h * 64;
    const bf16_t* vbase = vt + ((size_t)(b * HEADS + h) * 64) * SEQ;

    // staging: wave wv handles K instrs {wv*2, wv*2+1} and V instrs {wv*2, wv*2+1}.
    // lane ln -> row ln>>3 in 8-row group, pos ln&7 holds chunk (ln&7)^(ln>>3).
    int ar = lane >> 3;
    int ac = ((lane & 7) ^ ar) * 8;
    int i0 = wv * 2, i1 = wv * 2 + 1;
    const bf16_t* gK0 = kbase + (size_t)(i0 * 8 + ar) * QKVN + ac;
    const bf16_t* gK1 = kbase + (size_t)(i1 * 8 + ar) * QKVN + ac;
    const bf16_t* gV0 = vbase + (size_t)(i0 * 8 + ar) * SEQ + ac;
    const bf16_t* gV1 = vbase + (size_t)(i1 * 8 + ar) * SEQ + ac;

    auto stage = [&](int buf, int kb) {
        gload16(gK0 + (size_t)kb * QKVN, &Ks[buf][i0 * 8 * 64]);
        gload16(gK1 + (size_t)kb * QKVN, &Ks[buf][i1 * 8 * 64]);
        gload16(gV0 + kb, &Vs[buf][i0 * 8 * 64]);
        gload16(gV1 + kb, &Vs[buf][i1 * 8 * 64]);
    };

    stage(0, 0);
    int p0 = (quad ^ (l16 & 7)) * 8;         // chunks 0..3 (swizzled)
    int p1 = ((quad + 4) ^ (l16 & 7)) * 8;   // chunks 4..7 (swizzled)

    for (int it = 0; it < SEQ / 64; it++) {
        __syncthreads();
        if (it + 1 < SEQ / 64) stage((it + 1) & 1, (it + 1) * 64);
        const bf16_t* ks = Ks[it & 1];
        const bf16_t* vs = Vs[it & 1];

        f32x4 s[4];
        #pragma unroll
        for (int tt = 0; tt < 4; tt++) {
            const bf16_t* kr = &ks[(tt * 16 + l16) * 64];
            f32x4 z = {};
            z = __builtin_amdgcn_mfma_f32_16x16x32_bf16(ld8(kr + p0), qf0, z, 0, 0, 0);
            z = __builtin_amdgcn_mfma_f32_16x16x32_bf16(ld8(kr + p1), qf1, z, 0, 0, 0);
            s[tt] = z;   // s[tt][r]: key=it*64+tt*16+quad*4+r, query=l16
        }
        float mx = -3e38f;
        #pragma unroll
        for (int tt = 0; tt < 4; tt++)
            #pragma unroll
            for (int r = 0; r < 4; r++) {
                s[tt][r] *= 0.125f;
                mx = fmaxf(mx, s[tt][r]);
            }
        mx = fmaxf(mx, __shfl_xor(mx, 16));
        mx = fmaxf(mx, __shfl_xor(mx, 32));
        float mn = fmaxf(m, mx);
        float alpha = exp2f((m - mn) * LOG2E);
        m = mn;
        float nb = mn * LOG2E;
        float rs = 0.0f;
        #pragma unroll
        for (int tt = 0; tt < 4; tt++) {
            bf16x4 pkt;
            #pragma unroll
            for (int r = 0; r < 4; r++) {
                float p = exp2f(fmaf(s[tt][r], LOG2E, -nb));
                rs += p;
                pkt[r] = (bf16_t)p;
            }
            *(bf16x4*)&P[l16 * 72 + tt * 16 + quad * 4] = pkt;
        }
        l = l * alpha + rs;   // quad-partial; reduced at end
        #pragma unroll
        for (int jt = 0; jt < 4; jt++) o[jt] *= alpha;
        asm volatile("s_waitcnt lgkmcnt(0)" ::: "memory");  // per-wave P visible
        bf16x8 pf0 = ld8(&P[l16 * 72 + quad * 8]);
        bf16x8 pf1 = ld8(&P[l16 * 72 + 32 + quad * 8]);
        #pragma unroll
        for (int jt = 0; jt < 4; jt++) {
            const bf16_t* vr = &vs[(jt * 16 + l16) * 64];
            o[jt] = __builtin_amdgcn_mfma_f32_16x16x32_bf16(ld8(vr + p0), pf0, o[jt], 0, 0, 0);
            o[jt] = __builtin_amdgcn_mfma_f32_16x16x32_bf16(ld8(vr + p1), pf1, o[jt], 0, 0, 0);
        }
    }

    l += __shfl_xor(l, 16);
    l += __shfl_xor(l, 32);
    float inv = 1.0f / l;
    bf16_t* orow = out + (bS + qw0 + l16) * DIM + h * 64;
    #pragma unroll
    for (int jt = 0; jt < 4; jt++) {
        bf16x4 ov;
        #pragma unroll
        for (int r = 0; r < 4; r++) ov[r] = (bf16_t)(o[jt][r] * inv);
        *(bf16x4*)&orow[jt * 16 + quad * 4] = ov;
    }
}

extern "C" void kernel_launch(void* const* d_in, const int* in_sizes, int n_in,
                              void* d_out, int out_size, void* d_ws, size_t ws_size,
                              hipStream_t stream) {
    const float* x     = (const float*)d_in[0];
    const float* ln1_w = (const float*)d_in[1];
    const float* ln1_b = (const float*)d_in[2];
    const float* w_qkv = (const float*)d_in[3];
    const float* w_o   = (const float*)d_in[4];
    const float* b_o   = (const float*)d_in[5];
    const float* ln2_w = (const float*)d_in[6];
    const float* ln2_b = (const float*)d_in[7];
    const float* w1    = (const float*)d_in[8];
    const float* b1    = (const float*)d_in[9];
    const float* w2    = (const float*)d_in[10];
    const float* b2    = (const float*)d_in[11];
    float* out = (float*)d_out;

    char* ws = (char*)d_ws;
    size_t off = 0;
    auto alloc = [&](size_t bytes) -> char* {
        char* p = ws + off;
        off += (bytes + 255) & ~(size_t)255;
        return p;
    };
    bf16_t* wqkv_t = (bf16_t*)alloc((size_t)DEPTH * DIM * QKVN * 2);
    bf16_t* wo_t   = (bf16_t*)alloc((size_t)DEPTH * DIM * DIM * 2);
    bf16_t* w1_t   = (bf16_t*)alloc((size_t)DEPTH * DIM * MLPD * 2);
    bf16_t* w2_t   = (bf16_t*)alloc((size_t)DEPTH * MLPD * DIM * 2);
    bf16_t* hbuf   = (bf16_t*)alloc((size_t)MTOT * DIM * 2);
    bf16_t* qkvb   = (bf16_t*)alloc((size_t)MTOT * QKVN * 2);   // also Pp slice 0/1
    bf16_t* vtb    = (bf16_t*)alloc((size_t)BATCH * HEADS * 64 * SEQ * 2);
    bf16_t* aob    = (bf16_t*)alloc((size_t)MTOT * DIM * 2);
    bf16_t* midb   = (bf16_t*)alloc((size_t)MTOT * MLPD * 2);
    float*  Pm     = (float*)alloc((size_t)4 * MTOT * DIM * 4); // MLP2 partials
    float*  Pp     = (float*)qkvb;  // proj partials alias dead qkvb+vtb region
    if (off > ws_size) return;

    tcvt_kernel<<<dim3(QKVN / 32, DIM / 32, DEPTH), 256, 0, stream>>>(w_qkv, wqkv_t, DIM, QKVN);
    tcvt_kernel<<<dim3(DIM / 32,  DIM / 32, DEPTH), 256, 0, stream>>>(w_o,   wo_t,   DIM, DIM);
    tcvt_kernel<<<dim3(MLPD / 32, DIM / 32, DEPTH), 256, 0, stream>>>(w1,    w1_t,   DIM, MLPD);
    tcvt_kernel<<<dim3(DIM / 32, MLPD / 32, DEPTH), 256, 0, stream>>>(w2,    w2_t,   MLPD, DIM);

    hipMemcpyAsync(out, x, (size_t)MTOT * DIM * 4, hipMemcpyDeviceToDevice, stream);

    // initial LN1 (layer 0)
    lnr_kernel<<<MTOT, 192, 0, stream>>>(out, out, nullptr, 0, nullptr,
                                         ln1_w, ln1_b, hbuf, 1);

    for (int L = 0; L < DEPTH; L++) {
        // QKV: 36x16 = 576 blocks (single round)
        gemm_kernel<0><<<dim3(QKVN / 64, MTOT / 256, 1), 512, 0, stream>>>(
            hbuf, wqkv_t + (size_t)L * DIM * QKVN, nullptr, qkvb, nullptr, vtb,
            QKVN, DIM, DIM);
        attn_kernel<<<dim3(SEQ / 64, HEADS, BATCH), 256, 0, stream>>>(qkvb, vtb, aob);
        // proj: 12x16x2 = 384 blocks, split-K=2
        gemm_kernel<2><<<dim3(DIM / 64, MTOT / 256, 2), 512, 0, stream>>>(
            aob, wo_t + (size_t)L * DIM * DIM, nullptr, nullptr, Pp, nullptr,
            DIM, DIM, 384);
        lnr_kernel<<<MTOT, 192, 0, stream>>>(out, out, Pp, 2, b_o + L * DIM,
                                             ln2_w + L * DIM, ln2_b + L * DIM, hbuf, 1);
        // MLP1: 48x16 = 768 blocks (single round)
        gemm_kernel<1><<<dim3(MLPD / 64, MTOT / 256, 1), 512, 0, stream>>>(
            hbuf, w1_t + (size_t)L * DIM * MLPD, b1 + L * MLPD, midb, nullptr, nullptr,
            MLPD, DIM, DIM);
        // MLP2: 12x16x4 = 768 blocks, split-K=4
        gemm_kernel<2><<<dim3(DIM / 64, MTOT / 256, 4), 512, 0, stream>>>(
            midb, w2_t + (size_t)L * MLPD * DIM, nullptr, nullptr, Pm, nullptr,
            DIM, MLPD, 768);
        if (L < DEPTH - 1) {
            lnr_kernel<<<MTOT, 192, 0, stream>>>(out, out, Pm, 4, b2 + L * DIM,
                                                 ln1_w + (L + 1) * DIM,
                                                 ln1_b + (L + 1) * DIM, hbuf, 1);
        } else {
            lnr_kernel<<<MTOT, 192, 0, stream>>>(out, out, Pm, 4, b2 + L * DIM,
                                                 ln1_w, ln1_b, hbuf, 0);
        }
    }
}